// Round 11
// baseline (227.979 us; speedup 1.0000x reference)
//
#include <hip/hip_runtime.h>
#include <math.h>

#define NN 10000
#define EE 160000
#define ET 170000
#define FIN 256
#define HH 8
#define CC 64
#define HC 512
#define NCLS 40
#define ELLW 96

typedef unsigned short u16;
typedef unsigned int u32;
typedef _Float16 f16;
using f16x8 = __attribute__((ext_vector_type(8))) _Float16;
using f32x4 = __attribute__((ext_vector_type(4))) float;

#define MFMA16(a, b, c) __builtin_amdgcn_mfma_f32_16x16x32_f16((a), (b), (c), 0, 0, 0)

// ---------- prep: ELL scatter (blocks 0..664) + weight transposes ----------
#define SCAT_BLOCKS 665
__global__ __launch_bounds__(256) void prep_kernel(const int* __restrict__ ei,
                                                   int* __restrict__ cnt,
                                                   int* __restrict__ ell,
                                                   const float* __restrict__ W0,
                                                   const float* __restrict__ W1,
                                                   const float* __restrict__ W2,
                                                   f16* __restrict__ w0T,
                                                   f16* __restrict__ w1T,
                                                   f16* __restrict__ w2T) {
    int b = blockIdx.x;
    if (b < SCAT_BLOCKS) {
        int e = b * 256 + threadIdx.x;
        if (e >= ET) return;
        int s, d;
        if (e < EE) { s = ei[e]; d = ei[EE + e]; }
        else        { s = e - EE; d = s; }          // self-loops appended
        int pos = atomicAdd(&cnt[d], 1);
        if (pos < ELLW) ell[(size_t)d * ELLW + pos] = s;
        return;
    }
    int i = (b - SCAT_BLOCKS) * 256 + threadIdx.x;
    if (i < HC * FIN) {
        int n = i >> 8, k = i & 255;
        w0T[i] = (f16)W0[(size_t)k * HC + n];
    } else if (i < HC * FIN + HC * HC) {
        int j = i - HC * FIN;
        int n = j >> 9, k = j & 511;
        w1T[j] = (f16)W1[(size_t)k * HC + n];
    } else if (i < HC * FIN + HC * HC + NCLS * HC) {
        int j = i - HC * FIN - HC * HC;
        int n = j >> 9, k = j & 511;
        w2T[j] = (f16)W2[(size_t)k * NCLS + n];
    }
}

// ---------- GEMM + fused attn: B-resident LDS, barrier-free K-loop ----------
// hx2 output uses SLAB layout: slab s = [NN][128] f16 covering cols
// s*128..s*128+127 (head h -> slab h/2). Keeps each slab 2.56 MB (L2-fits).
template <int K, bool AF32>
__global__ __launch_bounds__(512) void gemm_attn(const void* __restrict__ Aptr,
                                                 const f16* __restrict__ BT,
                                                 const float* __restrict__ a_src,
                                                 const float* __restrict__ a_dst,
                                                 f16* __restrict__ hx2,
                                                 float* __restrict__ al_s,
                                                 float* __restrict__ al_d) {
    constexpr int KK = K / 32;            // MFMA K-steps (16 or 8)
    constexpr int CH = K / 8;             // 16B chunks per B row (64 or 32)
    __shared__ f16 Bs[64 * K];            // 64 KB (K=512) / 32 KB (K=256)
    int t = threadIdx.x;
    int hp = blockIdx.x;                  // head pair
    int lane = t & 63, w = t >> 6;
    int fm = lane & 15, g = lane >> 4;
    int bm = blockIdx.y * 128 + w * 16;
    int row = bm + fm;
    bool rok = row < NN;

    f16x8 af[KK];
    if (AF32) {
        const float* A = (const float*)Aptr;
#pragma unroll
        for (int kk = 0; kk < KK; ++kk) {
            float4 lo = make_float4(0.f, 0.f, 0.f, 0.f), hi = lo;
            if (rok) {
                const float* ap = A + (size_t)row * K + kk * 32 + g * 8;
                lo = *(const float4*)ap;
                hi = *(const float4*)(ap + 4);
            }
            f16x8 v;
            v[0] = (f16)lo.x; v[1] = (f16)lo.y; v[2] = (f16)lo.z; v[3] = (f16)lo.w;
            v[4] = (f16)hi.x; v[5] = (f16)hi.y; v[6] = (f16)hi.z; v[7] = (f16)hi.w;
            af[kk] = v;
        }
    } else {
        const f16* A = (const f16*)Aptr;
#pragma unroll
        for (int kk = 0; kk < KK; ++kk) {
            uint4 r = rok ? *(const uint4*)(A + (size_t)row * K + kk * 32 + g * 8)
                          : make_uint4(0u, 0u, 0u, 0u);
            af[kk] = __builtin_bit_cast(f16x8, r);
        }
    }

    for (int sl = 0; sl < 2; ++sl) {
        int h = hp * 2 + sl;
        const f16* bsrc = BT + (size_t)h * 64 * K;
        for (int c = t; c < 64 * CH; c += 512) {
            int brow = c / CH;
            int j = c - brow * CH;
            uint4 v = *(const uint4*)(bsrc + (size_t)brow * K + j * 8);
            *(uint4*)&Bs[(size_t)brow * K + ((j ^ (brow & 7)) * 8)] = v;
        }
        __syncthreads();

        f32x4 acc[4] = {};
#pragma unroll
        for (int kk = 0; kk < KK; ++kk) {
#pragma unroll
            for (int nt = 0; nt < 4; ++nt) {
                f16x8 b = *(const f16x8*)
                    &Bs[(nt * 16 + fm) * K + (((kk * 4 + g) ^ (fm & 7)) * 8)];
                acc[nt] = MFMA16(af[kk], b, acc[nt]);
            }
        }

        float asc[4], adc[4];
#pragma unroll
        for (int nt = 0; nt < 4; ++nt) {
            asc[nt] = a_src[h * 64 + nt * 16 + fm];
            adc[nt] = a_dst[h * 64 + nt * 16 + fm];
        }
        // slab write base for this head
        f16* hxslab = hx2 + ((size_t)(h >> 1) * NN) * 128 + (h & 1) * 64;
#pragma unroll
        for (int r = 0; r < 4; ++r) {
            int orow = bm + g * 4 + r;          // C/D: row=(lane>>4)*4+reg
            float s = acc[0][r] * asc[0] + acc[1][r] * asc[1] +
                      acc[2][r] * asc[2] + acc[3][r] * asc[3];
            float d = acc[0][r] * adc[0] + acc[1][r] * adc[1] +
                      acc[2][r] * adc[2] + acc[3][r] * adc[3];
#pragma unroll
            for (int off = 1; off < 16; off <<= 1) {
                s += __shfl_xor(s, off);
                d += __shfl_xor(d, off);
            }
            if (orow < NN) {
                if (fm == 0) {
                    al_s[orow * 8 + h] = s;
                    al_d[orow * 8 + h] = d;
                }
#pragma unroll
                for (int nt = 0; nt < 4; ++nt)
                    hxslab[(size_t)orow * 128 + nt * 16 + fm] = (f16)acc[nt][r];
            }
        }
        __syncthreads();
    }
}

// ---------- layer 2: barrier-free B-resident GEMM 512->40 + fused attn ------
__global__ __launch_bounds__(256) void gemm2_attn(const f16* __restrict__ A,
                                                  const f16* __restrict__ BT,
                                                  const float* __restrict__ a_src2,
                                                  const float* __restrict__ a_dst2,
                                                  float* __restrict__ hx40,
                                                  float* __restrict__ als2,
                                                  float* __restrict__ ald2) {
    __shared__ f16 Bs[48 * HC];    // 48 KB, rows 40..47 zero
    int t = threadIdx.x;
    int lane = t & 63, w = t >> 6;
    int fm = lane & 15, g = lane >> 4;
    int bm = blockIdx.x * 64 + w * 16;
    int row = bm + fm;
    bool rok = row < NN;

    for (int c = t; c < 48 * 64; c += 256) {
        int brow = c >> 6, j = c & 63;
        uint4 v = make_uint4(0u, 0u, 0u, 0u);
        if (brow < NCLS) v = *(const uint4*)(BT + (size_t)brow * HC + j * 8);
        *(uint4*)&Bs[brow * HC + ((j ^ (brow & 7)) * 8)] = v;
    }

    f16x8 af[16];
#pragma unroll
    for (int kk = 0; kk < 16; ++kk) {
        uint4 r = rok ? *(const uint4*)(A + (size_t)row * HC + kk * 32 + g * 8)
                      : make_uint4(0u, 0u, 0u, 0u);
        af[kk] = __builtin_bit_cast(f16x8, r);
    }
    __syncthreads();

    f32x4 acc[3] = {};
#pragma unroll
    for (int kk = 0; kk < 16; ++kk) {
#pragma unroll
        for (int nt = 0; nt < 3; ++nt) {
            f16x8 b = *(const f16x8*)
                &Bs[(nt * 16 + fm) * HC + (((kk * 4 + g) ^ (fm & 7)) * 8)];
            acc[nt] = MFMA16(af[kk], b, acc[nt]);
        }
    }

    float a2s[3], a2d[3];
#pragma unroll
    for (int nt = 0; nt < 3; ++nt) {
        int col = nt * 16 + fm;
        a2s[nt] = (col < NCLS) ? a_src2[col] : 0.f;
        a2d[nt] = (col < NCLS) ? a_dst2[col] : 0.f;
    }
#pragma unroll
    for (int r = 0; r < 4; ++r) {
        int orow = bm + g * 4 + r;
        float s = acc[0][r] * a2s[0] + acc[1][r] * a2s[1] + acc[2][r] * a2s[2];
        float d = acc[0][r] * a2d[0] + acc[1][r] * a2d[1] + acc[2][r] * a2d[2];
#pragma unroll
        for (int off = 1; off < 16; off <<= 1) {
            s += __shfl_xor(s, off);
            d += __shfl_xor(d, off);
        }
        if (orow < NN) {
            if (fm == 0) { als2[orow] = s; ald2[orow] = d; }
#pragma unroll
            for (int nt = 0; nt < 3; ++nt) {
                int col = nt * 16 + fm;
                if (col < NCLS) hx40[(size_t)orow * NCLS + col] = acc[nt][r];
            }
        }
    }
}

// ---------- aggregate over slab-partitioned hx2: (node, slab) jobs ----------
// grid = 10000 blocks, slab-major: blocks [slab*2500, slab*2500+2500) handle
// slab `slab` for 4 nodes each (1 wave per node-slab job). Each slab is
// 2.56 MB -> fits per-XCD L2; dispatch-order phase locality keeps co-resident
// blocks on the same slab => gather becomes L2-resident.
// Wave layout: 4 edge-groups x 16 lanes; each group gathers one edge's
// 128-ch slice (16 lanes x 16 B = 256 B); cross-group combine via shfl_xor.
__global__ __launch_bounds__(256) void agg_slab(const f16* __restrict__ hx2,
                                                const float* __restrict__ al_s,
                                                const float* __restrict__ al_d,
                                                const int* __restrict__ cnt,
                                                const int* __restrict__ ell,
                                                const float* __restrict__ bias,
                                                f16* __restrict__ outF) {
    int j = blockIdx.x;
    int slab = j / 2500;
    int nb = j - slab * 2500;
    int lane = threadIdx.x & 63, w = threadIdx.x >> 6;
    int n = nb * 4 + w;                 // < 10000 always
    int grp = lane >> 4, li = lane & 15;
    int h = slab * 2 + (li >> 3);       // head for this lane's channels
    const f16* slabp = hx2 + (size_t)slab * NN * 128;
    float ald = al_d[n * HH + h];
    int dg = cnt[n]; if (dg > ELLW) dg = ELLW;
    const int* ep = ell + (size_t)n * ELLW;
    float acc[8] = {0.f, 0.f, 0.f, 0.f, 0.f, 0.f, 0.f, 0.f};
    float den = 0.f;
#pragma unroll 2
    for (int base = 0; base < dg; base += 4) {
        int i = base + grp;
        bool valid = i < dg;
        int s = valid ? ep[i] : 0;
        float e = al_s[s * HH + h] + ald;
        e = e > 0.f ? e : 0.2f * e;     // leaky_relu
        float wt = valid ? __expf(e) : 0.f;
        uint4 raw = *(const uint4*)(slabp + (size_t)s * 128 + li * 8);
        f16x8 f = __builtin_bit_cast(f16x8, raw);
#pragma unroll
        for (int c = 0; c < 8; ++c) acc[c] += wt * (float)f[c];
        den += wt;
    }
    // combine the 4 edge-groups (li, and thus channel/head, invariant)
    den += __shfl_xor(den, 16);
    den += __shfl_xor(den, 32);
#pragma unroll
    for (int c = 0; c < 8; ++c) {
        acc[c] += __shfl_xor(acc[c], 16);
        acc[c] += __shfl_xor(acc[c], 32);
    }
    if (grp == 0) {
        int col = slab * 128 + li * 8;
        float inv = 1.f / (den + 1e-16f);
        float4 b0v = *(const float4*)(bias + col);
        float4 b1v = *(const float4*)(bias + col + 4);
        float bb[8] = {b0v.x, b0v.y, b0v.z, b0v.w, b1v.x, b1v.y, b1v.z, b1v.w};
        f16x8 o;
#pragma unroll
        for (int c = 0; c < 8; ++c) {
            float v = acc[c] * inv + bb[c];
            v = v > 0.f ? v : expm1f(v);        // ELU
            o[c] = (f16)v;
        }
        *(uint4*)(outF + (size_t)n * HC + col) = __builtin_bit_cast(uint4, o);
    }
}

// ---------- final aggregate (H=1, C=40), fp32, no ELU ----------
__global__ __launch_bounds__(64) void agg2_final(const float* __restrict__ hx40,
                                                 const float* __restrict__ als,
                                                 const float* __restrict__ aldp,
                                                 const int* __restrict__ cnt,
                                                 const int* __restrict__ ell,
                                                 const float* __restrict__ b2,
                                                 float* __restrict__ out) {
    int n = blockIdx.x;
    int c = threadIdx.x;
    float ald = aldp[n];
    int dg = cnt[n]; if (dg > ELLW) dg = ELLW;
    const int* ep = ell + (size_t)n * ELLW;
    float acc = 0.f, den = 0.f;
    int i = 0;
    for (; i + 4 <= dg; i += 4) {
        int s0 = ep[i], s1 = ep[i + 1], s2 = ep[i + 2], s3 = ep[i + 3];
        float e0 = als[s0], e1 = als[s1], e2 = als[s2], e3 = als[s3];
        float v0 = 0.f, v1 = 0.f, v2 = 0.f, v3 = 0.f;
        if (c < NCLS) {
            v0 = hx40[(size_t)s0 * NCLS + c];
            v1 = hx40[(size_t)s1 * NCLS + c];
            v2 = hx40[(size_t)s2 * NCLS + c];
            v3 = hx40[(size_t)s3 * NCLS + c];
        }
        e0 += ald; e0 = e0 > 0.f ? e0 : 0.2f * e0;
        e1 += ald; e1 = e1 > 0.f ? e1 : 0.2f * e1;
        e2 += ald; e2 = e2 > 0.f ? e2 : 0.2f * e2;
        e3 += ald; e3 = e3 > 0.f ? e3 : 0.2f * e3;
        float w0 = __expf(e0), w1 = __expf(e1), w2 = __expf(e2), w3 = __expf(e3);
        acc += w0 * v0 + w1 * v1 + w2 * v2 + w3 * v3;
        den += w0 + w1 + w2 + w3;
    }
    for (; i < dg; ++i) {
        int s = ep[i];
        float e = als[s] + ald;
        e = e > 0.f ? e : 0.2f * e;
        float wgt = __expf(e);
        if (c < NCLS) acc += wgt * hx40[(size_t)s * NCLS + c];
        den += wgt;
    }
    if (c < NCLS) out[(size_t)n * NCLS + c] = acc / (den + 1e-16f) + b2[c];
}

extern "C" void kernel_launch(void* const* d_in, const int* in_sizes, int n_in,
                              void* d_out, int out_size, void* d_ws, size_t ws_size,
                              hipStream_t stream) {
    const float* x   = (const float*)d_in[0];
    const int*   ei  = (const int*)  d_in[1];
    const float* W0  = (const float*)d_in[2];
    const float* as0 = (const float*)d_in[3];
    const float* ad0 = (const float*)d_in[4];
    const float* b0  = (const float*)d_in[5];
    const float* W1  = (const float*)d_in[6];
    const float* as1 = (const float*)d_in[7];
    const float* ad1 = (const float*)d_in[8];
    const float* b1  = (const float*)d_in[9];
    const float* W2  = (const float*)d_in[10];
    const float* as2 = (const float*)d_in[11];
    const float* ad2 = (const float*)d_in[12];
    const float* b2  = (const float*)d_in[13];
    float* out = (float*)d_out;

    char* p = (char*)d_ws;
    int* cnt  = (int*)p; p += 40064;
    int* ell  = (int*)p; p += (size_t)NN * ELLW * 4;    // 3.84 MB
    f16* w0T  = (f16*)p; p += HC * FIN * 2;
    f16* w1T  = (f16*)p; p += HC * HC * 2;
    f16* w2T  = (f16*)p; p += NCLS * HC * 2;
    f16* hxA  = (f16*)p; p += (size_t)NN * HC * 2;      // slab layout
    f16* hxB  = (f16*)p; p += (size_t)NN * HC * 2;      // slab layout
    f16* fA   = (f16*)p; p += (size_t)NN * HC * 2;
    f16* fB   = (f16*)p; p += (size_t)NN * HC * 2;
    float* hx40 = (float*)p; p += (size_t)NN * NCLS * 4;
    float* als0 = (float*)p; p += NN * HH * 4;
    float* ald0 = (float*)p; p += NN * HH * 4;
    float* als1 = (float*)p; p += NN * HH * 4;
    float* ald1 = (float*)p; p += NN * HH * 4;
    float* als2 = (float*)p; p += NN * 4;
    float* ald2 = (float*)p; p += NN * 4;

    const int NBR = (NN + 127) / 128;   // 79 row-chunks (layers 0/1)
    const int NB2 = (NN + 63) / 64;     // 157 row-blocks (layer 2)
    const int NPREP = SCAT_BLOCKS + (HC * FIN + HC * HC + NCLS * HC + 255) / 256;

    hipMemsetAsync(cnt, 0, NN * sizeof(int), stream);
    prep_kernel<<<NPREP, 256, 0, stream>>>(ei, cnt, ell, W0, W1, W2, w0T, w1T, w2T);

    dim3 gA(4, NBR);   // 4 head-pairs x 79 row-chunks = 316 blocks
    // layer 0: GEMM(fp32 x -> f16 frags) + attn epilogue; then slab aggregate
    gemm_attn<FIN, true><<<gA, 512, 0, stream>>>(x, w0T, as0, ad0, hxA, als0, ald0);
    agg_slab<<<10000, 256, 0, stream>>>(hxA, als0, ald0, cnt, ell, b0, fA);
    // layer 1
    gemm_attn<HC, false><<<gA, 512, 0, stream>>>(fA, w1T, as1, ad1, hxB, als1, ald1);
    agg_slab<<<10000, 256, 0, stream>>>(hxB, als1, ald1, cnt, ell, b1, fB);
    // layer 2
    gemm2_attn<<<NB2, 256, 0, stream>>>(fB, w2T, as2, ad2, hx40, als2, ald2);
    agg2_final<<<NN, 64, 0, stream>>>(hx40, als2, ald2, cnt, ell, b2, out);
}

// Round 12
// 213.930 us; speedup vs baseline: 1.0657x; 1.0657x over previous
//
#include <hip/hip_runtime.h>
#include <math.h>

#define NN 10000
#define EE 160000
#define ET 170000
#define FIN 256
#define HH 8
#define CC 64
#define HC 512
#define NCLS 40
#define ELLW 96

typedef unsigned short u16;
typedef unsigned int u32;
typedef _Float16 f16;
using f16x8 = __attribute__((ext_vector_type(8))) _Float16;
using f32x4 = __attribute__((ext_vector_type(4))) float;

#define MFMA16(a, b, c) __builtin_amdgcn_mfma_f32_16x16x32_f16((a), (b), (c), 0, 0, 0)

// ---------- ELL scatter ----------
__global__ __launch_bounds__(256) void scatter_ell(const int* __restrict__ ei,
                                                   int* __restrict__ cnt,
                                                   int* __restrict__ ell) {
    int e = blockIdx.x * 256 + threadIdx.x;
    if (e >= ET) return;
    int s, d;
    if (e < EE) { s = ei[e]; d = ei[EE + e]; }
    else        { s = e - EE; d = s; }          // self-loops appended
    int pos = atomicAdd(&cnt[d], 1);
    if (pos < ELLW) ell[(size_t)d * ELLW + pos] = s;
}

// ---------- coalesced weight transpose via 32x32 LDS tile ----------
// W [K][N] fp32 -> WT [N][K] f16. Grid: (K/32) x (N/32) tiles (padded).
__global__ __launch_bounds__(256) void transpose_w(const float* __restrict__ W,
                                                   f16* __restrict__ WT,
                                                   int K, int N) {
    __shared__ f16 tile[32][33];
    int tk = blockIdx.x * 32, tn = blockIdx.y * 32;
    int lx = threadIdx.x & 31, ly = threadIdx.x >> 5;   // 32 x 8
#pragma unroll
    for (int r = 0; r < 4; ++r) {
        int k = tk + ly + r * 8, n = tn + lx;
        tile[ly + r * 8][lx] = (k < K && n < N) ? (f16)W[(size_t)k * N + n] : (f16)0.f;
    }
    __syncthreads();
#pragma unroll
    for (int r = 0; r < 4; ++r) {
        int n = tn + ly + r * 8, k = tk + lx;
        if (n < N && k < K) WT[(size_t)n * K + k] = tile[lx][ly + r * 8];
    }
}

// ---------- GEMM + fused attn: B-resident LDS, barrier-free K-loop ----------
template <int K, bool AF32>
__global__ __launch_bounds__(512) void gemm_attn(const void* __restrict__ Aptr,
                                                 const f16* __restrict__ BT,
                                                 const float* __restrict__ a_src,
                                                 const float* __restrict__ a_dst,
                                                 f16* __restrict__ hx2,
                                                 float* __restrict__ al_s,
                                                 float* __restrict__ al_d) {
    constexpr int KK = K / 32;            // MFMA K-steps (16 or 8)
    constexpr int CH = K / 8;             // 16B chunks per B row (64 or 32)
    __shared__ f16 Bs[64 * K];            // 64 KB (K=512) / 32 KB (K=256)
    int t = threadIdx.x;
    int hp = blockIdx.x;                  // head pair
    int lane = t & 63, w = t >> 6;
    int fm = lane & 15, g = lane >> 4;
    int bm = blockIdx.y * 128 + w * 16;
    int row = bm + fm;
    bool rok = row < NN;

    f16x8 af[KK];
    if (AF32) {
        const float* A = (const float*)Aptr;
#pragma unroll
        for (int kk = 0; kk < KK; ++kk) {
            float4 lo = make_float4(0.f, 0.f, 0.f, 0.f), hi = lo;
            if (rok) {
                const float* ap = A + (size_t)row * K + kk * 32 + g * 8;
                lo = *(const float4*)ap;
                hi = *(const float4*)(ap + 4);
            }
            f16x8 v;
            v[0] = (f16)lo.x; v[1] = (f16)lo.y; v[2] = (f16)lo.z; v[3] = (f16)lo.w;
            v[4] = (f16)hi.x; v[5] = (f16)hi.y; v[6] = (f16)hi.z; v[7] = (f16)hi.w;
            af[kk] = v;
        }
    } else {
        const f16* A = (const f16*)Aptr;
#pragma unroll
        for (int kk = 0; kk < KK; ++kk) {
            uint4 r = rok ? *(const uint4*)(A + (size_t)row * K + kk * 32 + g * 8)
                          : make_uint4(0u, 0u, 0u, 0u);
            af[kk] = __builtin_bit_cast(f16x8, r);
        }
    }

    for (int sl = 0; sl < 2; ++sl) {
        int h = hp * 2 + sl;
        const f16* bsrc = BT + (size_t)h * 64 * K;
        for (int c = t; c < 64 * CH; c += 512) {
            int brow = c / CH;
            int j = c - brow * CH;
            uint4 v = *(const uint4*)(bsrc + (size_t)brow * K + j * 8);
            *(uint4*)&Bs[(size_t)brow * K + ((j ^ (brow & 7)) * 8)] = v;
        }
        __syncthreads();

        f32x4 acc[4] = {};
#pragma unroll
        for (int kk = 0; kk < KK; ++kk) {
#pragma unroll
            for (int nt = 0; nt < 4; ++nt) {
                f16x8 b = *(const f16x8*)
                    &Bs[(nt * 16 + fm) * K + (((kk * 4 + g) ^ (fm & 7)) * 8)];
                acc[nt] = MFMA16(af[kk], b, acc[nt]);
            }
        }

        float asc[4], adc[4];
#pragma unroll
        for (int nt = 0; nt < 4; ++nt) {
            asc[nt] = a_src[h * 64 + nt * 16 + fm];
            adc[nt] = a_dst[h * 64 + nt * 16 + fm];
        }
#pragma unroll
        for (int r = 0; r < 4; ++r) {
            int orow = bm + g * 4 + r;          // C/D: row=(lane>>4)*4+reg
            float s = acc[0][r] * asc[0] + acc[1][r] * asc[1] +
                      acc[2][r] * asc[2] + acc[3][r] * asc[3];
            float d = acc[0][r] * adc[0] + acc[1][r] * adc[1] +
                      acc[2][r] * adc[2] + acc[3][r] * adc[3];
#pragma unroll
            for (int off = 1; off < 16; off <<= 1) {
                s += __shfl_xor(s, off);
                d += __shfl_xor(d, off);
            }
            if (orow < NN) {
                if (fm == 0) {
                    al_s[orow * 8 + h] = s;
                    al_d[orow * 8 + h] = d;
                }
#pragma unroll
                for (int nt = 0; nt < 4; ++nt)
                    hx2[(size_t)orow * HC + h * 64 + nt * 16 + fm] =
                        (f16)acc[nt][r];
            }
        }
        __syncthreads();
    }
}

// ---------- layer 2: barrier-free B-resident GEMM 512->40 + fused attn ------
__global__ __launch_bounds__(256) void gemm2_attn(const f16* __restrict__ A,
                                                  const f16* __restrict__ BT,
                                                  const float* __restrict__ a_src2,
                                                  const float* __restrict__ a_dst2,
                                                  float* __restrict__ hx40,
                                                  float* __restrict__ als2,
                                                  float* __restrict__ ald2) {
    __shared__ f16 Bs[48 * HC];    // 48 KB, rows 40..47 zero
    int t = threadIdx.x;
    int lane = t & 63, w = t >> 6;
    int fm = lane & 15, g = lane >> 4;
    int bm = blockIdx.x * 64 + w * 16;
    int row = bm + fm;
    bool rok = row < NN;

    for (int c = t; c < 48 * 64; c += 256) {
        int brow = c >> 6, j = c & 63;
        uint4 v = make_uint4(0u, 0u, 0u, 0u);
        if (brow < NCLS) v = *(const uint4*)(BT + (size_t)brow * HC + j * 8);
        *(uint4*)&Bs[brow * HC + ((j ^ (brow & 7)) * 8)] = v;
    }

    f16x8 af[16];
#pragma unroll
    for (int kk = 0; kk < 16; ++kk) {
        uint4 r = rok ? *(const uint4*)(A + (size_t)row * HC + kk * 32 + g * 8)
                      : make_uint4(0u, 0u, 0u, 0u);
        af[kk] = __builtin_bit_cast(f16x8, r);
    }
    __syncthreads();

    f32x4 acc[3] = {};
#pragma unroll
    for (int kk = 0; kk < 16; ++kk) {
#pragma unroll
        for (int nt = 0; nt < 3; ++nt) {
            f16x8 b = *(const f16x8*)
                &Bs[(nt * 16 + fm) * HC + (((kk * 4 + g) ^ (fm & 7)) * 8)];
            acc[nt] = MFMA16(af[kk], b, acc[nt]);
        }
    }

    float a2s[3], a2d[3];
#pragma unroll
    for (int nt = 0; nt < 3; ++nt) {
        int col = nt * 16 + fm;
        a2s[nt] = (col < NCLS) ? a_src2[col] : 0.f;
        a2d[nt] = (col < NCLS) ? a_dst2[col] : 0.f;
    }
#pragma unroll
    for (int r = 0; r < 4; ++r) {
        int orow = bm + g * 4 + r;
        float s = acc[0][r] * a2s[0] + acc[1][r] * a2s[1] + acc[2][r] * a2s[2];
        float d = acc[0][r] * a2d[0] + acc[1][r] * a2d[1] + acc[2][r] * a2d[2];
#pragma unroll
        for (int off = 1; off < 16; off <<= 1) {
            s += __shfl_xor(s, off);
            d += __shfl_xor(d, off);
        }
        if (orow < NN) {
            if (fm == 0) { als2[orow] = s; ald2[orow] = d; }
#pragma unroll
            for (int nt = 0; nt < 3; ++nt) {
                int col = nt * 16 + fm;
                if (col < NCLS) hx40[(size_t)orow * NCLS + col] = acc[nt][r];
            }
        }
    }
}

// ---------- aggregate: 2 WAVES per node (even/odd ELL slots), LDS combine ----
__global__ __launch_bounds__(256) void agg_ell(const f16* __restrict__ hx2,
                                               const float* __restrict__ al_s,
                                               const float* __restrict__ al_d,
                                               const int* __restrict__ cnt,
                                               const int* __restrict__ ell,
                                               const float* __restrict__ bias,
                                               f16* __restrict__ outF) {
    __shared__ float accbuf[2][64][8];
    __shared__ float denbuf[2][64];
    int t = threadIdx.x;
    int lane = t & 63, w = t >> 6;
    int p = w >> 1, sub = w & 1;
    int n = blockIdx.x * 2 + p;
    bool nok = n < NN;
    int ch = lane * 8;          // 8 channels per lane; 64 lanes = 512 ch
    int h = lane >> 3;
    float acc[8] = {0.f, 0.f, 0.f, 0.f, 0.f, 0.f, 0.f, 0.f};
    float den = 0.f;
    if (nok) {
        float ald = al_d[n * HH + h];
        int dg = cnt[n]; if (dg > ELLW) dg = ELLW;
        const int* ep = ell + (size_t)n * ELLW;
        int i = sub;
        for (; i + 6 < dg; i += 8) {     // edges i, i+2, i+4, i+6
            int s0 = ep[i], s1 = ep[i + 2], s2 = ep[i + 4], s3 = ep[i + 6];
            float e0 = al_s[s0 * HH + h], e1 = al_s[s1 * HH + h];
            float e2 = al_s[s2 * HH + h], e3 = al_s[s3 * HH + h];
            uint4 v0 = *(const uint4*)(hx2 + (size_t)s0 * HC + ch);
            uint4 v1 = *(const uint4*)(hx2 + (size_t)s1 * HC + ch);
            uint4 v2 = *(const uint4*)(hx2 + (size_t)s2 * HC + ch);
            uint4 v3 = *(const uint4*)(hx2 + (size_t)s3 * HC + ch);
            e0 += ald; e0 = e0 > 0.f ? e0 : 0.2f * e0;
            e1 += ald; e1 = e1 > 0.f ? e1 : 0.2f * e1;
            e2 += ald; e2 = e2 > 0.f ? e2 : 0.2f * e2;
            e3 += ald; e3 = e3 > 0.f ? e3 : 0.2f * e3;
            float w0 = __expf(e0), w1 = __expf(e1);
            float w2 = __expf(e2), w3 = __expf(e3);
            f16x8 f0 = __builtin_bit_cast(f16x8, v0);
            f16x8 f1 = __builtin_bit_cast(f16x8, v1);
            f16x8 f2 = __builtin_bit_cast(f16x8, v2);
            f16x8 f3 = __builtin_bit_cast(f16x8, v3);
#pragma unroll
            for (int j = 0; j < 8; ++j)
                acc[j] += w0 * (float)f0[j] + w1 * (float)f1[j] +
                          w2 * (float)f2[j] + w3 * (float)f3[j];
            den += w0 + w1 + w2 + w3;
        }
        for (; i < dg; i += 2) {
            int s = ep[i];
            float e = al_s[s * HH + h] + ald;
            e = e > 0.f ? e : 0.2f * e;
            float wgt = __expf(e);
            uint4 v = *(const uint4*)(hx2 + (size_t)s * HC + ch);
            f16x8 f = __builtin_bit_cast(f16x8, v);
#pragma unroll
            for (int j = 0; j < 8; ++j) acc[j] += wgt * (float)f[j];
            den += wgt;
        }
    }
    if (sub == 1) {
#pragma unroll
        for (int j = 0; j < 8; ++j) accbuf[p][lane][j] = acc[j];
        denbuf[p][lane] = den;
    }
    __syncthreads();
    if (sub == 0 && nok) {
#pragma unroll
        for (int j = 0; j < 8; ++j) acc[j] += accbuf[p][lane][j];
        den += denbuf[p][lane];
        float inv = 1.f / (den + 1e-16f);
        float4 b0v = *(const float4*)(bias + ch);
        float4 b1v = *(const float4*)(bias + ch + 4);
        float bb[8] = {b0v.x, b0v.y, b0v.z, b0v.w, b1v.x, b1v.y, b1v.z, b1v.w};
        f16x8 o;
#pragma unroll
        for (int j = 0; j < 8; ++j) {
            float v = acc[j] * inv + bb[j];
            v = v > 0.f ? v : expm1f(v);        // ELU
            o[j] = (f16)v;
        }
        *(uint4*)(outF + (size_t)n * HC + ch) = __builtin_bit_cast(uint4, o);
    }
}

// ---------- final aggregate (H=1, C=40), 4 nodes/block ----------
__global__ __launch_bounds__(256) void agg2_final(const float* __restrict__ hx40,
                                                  const float* __restrict__ als,
                                                  const float* __restrict__ aldp,
                                                  const int* __restrict__ cnt,
                                                  const int* __restrict__ ell,
                                                  const float* __restrict__ b2,
                                                  float* __restrict__ out) {
    int w = threadIdx.x >> 6, c = threadIdx.x & 63;
    int n = blockIdx.x * 4 + w;
    if (n >= NN) return;
    float ald = aldp[n];
    int dg = cnt[n]; if (dg > ELLW) dg = ELLW;
    const int* ep = ell + (size_t)n * ELLW;
    float acc = 0.f, den = 0.f;
    int i = 0;
    for (; i + 4 <= dg; i += 4) {
        int s0 = ep[i], s1 = ep[i + 1], s2 = ep[i + 2], s3 = ep[i + 3];
        float e0 = als[s0], e1 = als[s1], e2 = als[s2], e3 = als[s3];
        float v0 = 0.f, v1 = 0.f, v2 = 0.f, v3 = 0.f;
        if (c < NCLS) {
            v0 = hx40[(size_t)s0 * NCLS + c];
            v1 = hx40[(size_t)s1 * NCLS + c];
            v2 = hx40[(size_t)s2 * NCLS + c];
            v3 = hx40[(size_t)s3 * NCLS + c];
        }
        e0 += ald; e0 = e0 > 0.f ? e0 : 0.2f * e0;
        e1 += ald; e1 = e1 > 0.f ? e1 : 0.2f * e1;
        e2 += ald; e2 = e2 > 0.f ? e2 : 0.2f * e2;
        e3 += ald; e3 = e3 > 0.f ? e3 : 0.2f * e3;
        float w0 = __expf(e0), w1 = __expf(e1), w2 = __expf(e2), w3 = __expf(e3);
        acc += w0 * v0 + w1 * v1 + w2 * v2 + w3 * v3;
        den += w0 + w1 + w2 + w3;
    }
    for (; i < dg; ++i) {
        int s = ep[i];
        float e = als[s] + ald;
        e = e > 0.f ? e : 0.2f * e;
        float wgt = __expf(e);
        if (c < NCLS) acc += wgt * hx40[(size_t)s * NCLS + c];
        den += wgt;
    }
    if (c < NCLS) out[(size_t)n * NCLS + c] = acc / (den + 1e-16f) + b2[c];
}

extern "C" void kernel_launch(void* const* d_in, const int* in_sizes, int n_in,
                              void* d_out, int out_size, void* d_ws, size_t ws_size,
                              hipStream_t stream) {
    const float* x   = (const float*)d_in[0];
    const int*   ei  = (const int*)  d_in[1];
    const float* W0  = (const float*)d_in[2];
    const float* as0 = (const float*)d_in[3];
    const float* ad0 = (const float*)d_in[4];
    const float* b0  = (const float*)d_in[5];
    const float* W1  = (const float*)d_in[6];
    const float* as1 = (const float*)d_in[7];
    const float* ad1 = (const float*)d_in[8];
    const float* b1  = (const float*)d_in[9];
    const float* W2  = (const float*)d_in[10];
    const float* as2 = (const float*)d_in[11];
    const float* ad2 = (const float*)d_in[12];
    const float* b2  = (const float*)d_in[13];
    float* out = (float*)d_out;

    char* p = (char*)d_ws;
    int* cnt  = (int*)p; p += 40064;
    int* ell  = (int*)p; p += (size_t)NN * ELLW * 4;    // 3.84 MB
    f16* w0T  = (f16*)p; p += HC * FIN * 2;
    f16* w1T  = (f16*)p; p += HC * HC * 2;
    f16* w2T  = (f16*)p; p += NCLS * HC * 2;
    f16* hxA  = (f16*)p; p += (size_t)NN * HC * 2;
    f16* hxB  = (f16*)p; p += (size_t)NN * HC * 2;
    f16* fA   = (f16*)p; p += (size_t)NN * HC * 2;
    f16* fB   = (f16*)p; p += (size_t)NN * HC * 2;
    float* hx40 = (float*)p; p += (size_t)NN * NCLS * 4;
    float* als0 = (float*)p; p += NN * HH * 4;
    float* ald0 = (float*)p; p += NN * HH * 4;
    float* als1 = (float*)p; p += NN * HH * 4;
    float* ald1 = (float*)p; p += NN * HH * 4;
    float* als2 = (float*)p; p += NN * 4;
    float* ald2 = (float*)p; p += NN * 4;

    const int NBR = (NN + 127) / 128;   // 79 row-chunks (layers 0/1)
    const int NAG = (NN + 1) / 2;       // 5000 blocks (2 waves/node agg)
    const int NB2 = (NN + 63) / 64;     // 157 row-blocks (layer 2)

    hipMemsetAsync(cnt, 0, NN * sizeof(int), stream);
    scatter_ell<<<(ET + 255) / 256, 256, 0, stream>>>(ei, cnt, ell);
    // coalesced weight transposes (LDS tiled)
    transpose_w<<<dim3(FIN / 32, HC / 32), 256, 0, stream>>>(W0, w0T, FIN, HC);
    transpose_w<<<dim3(HC / 32, HC / 32), 256, 0, stream>>>(W1, w1T, HC, HC);
    transpose_w<<<dim3(HC / 32, (NCLS + 31) / 32), 256, 0, stream>>>(W2, w2T, HC, NCLS);

    dim3 gA(4, NBR);   // 4 head-pairs x 79 row-chunks = 316 blocks
    // layer 0
    gemm_attn<FIN, true><<<gA, 512, 0, stream>>>(x, w0T, as0, ad0, hxA, als0, ald0);
    agg_ell<<<NAG, 256, 0, stream>>>(hxA, als0, ald0, cnt, ell, b0, fA);
    // layer 1
    gemm_attn<HC, false><<<gA, 512, 0, stream>>>(fA, w1T, as1, ad1, hxB, als1, ald1);
    agg_ell<<<NAG, 256, 0, stream>>>(hxB, als1, ald1, cnt, ell, b1, fB);
    // layer 2
    gemm2_attn<<<NB2, 256, 0, stream>>>(fB, w2T, as2, ad2, hx40, als2, ald2);
    agg2_final<<<(NN + 3) / 4, 256, 0, stream>>>(hx40, als2, ald2, cnt, ell, b2, out);
}

// Round 13
// 208.638 us; speedup vs baseline: 1.0927x; 1.0254x over previous
//
#include <hip/hip_runtime.h>
#include <math.h>

#define NN 10000
#define EE 160000
#define ET 170000
#define FIN 256
#define HH 8
#define CC 64
#define HC 512
#define NCLS 40
#define ELLW 96

typedef unsigned short u16;
typedef unsigned int u32;
typedef _Float16 f16;
using f16x8 = __attribute__((ext_vector_type(8))) _Float16;
using f32x4 = __attribute__((ext_vector_type(4))) float;

#define MFMA16(a, b, c) __builtin_amdgcn_mfma_f32_16x16x32_f16((a), (b), (c), 0, 0, 0)

// ---------- fused prep: ELL scatter + coalesced weight transposes ----------
// blocks 0..664: scatter edges into ELL.
// blocks 665..1080: 32x32 LDS-tiled transpose of W0 (128 tiles), W1 (256),
// W2 (32) from fp32 [K][N] to f16 [N][K].
#define SCAT_BLOCKS 665
__global__ __launch_bounds__(256) void prep_kernel(const int* __restrict__ ei,
                                                   int* __restrict__ cnt,
                                                   int* __restrict__ ell,
                                                   const float* __restrict__ W0,
                                                   const float* __restrict__ W1,
                                                   const float* __restrict__ W2,
                                                   f16* __restrict__ w0T,
                                                   f16* __restrict__ w1T,
                                                   f16* __restrict__ w2T) {
    __shared__ f16 tile[32][33];
    int b = blockIdx.x;
    if (b < SCAT_BLOCKS) {
        int e = b * 256 + threadIdx.x;
        if (e >= ET) return;
        int s, d;
        if (e < EE) { s = ei[e]; d = ei[EE + e]; }
        else        { s = e - EE; d = s; }          // self-loops appended
        int pos = atomicAdd(&cnt[d], 1);
        if (pos < ELLW) ell[(size_t)d * ELLW + pos] = s;
        return;
    }
    int tb = b - SCAT_BLOCKS;
    const float* W; f16* WT; int K, N, tk, tn;
    if (tb < 128)      { W = W0; WT = w0T; K = FIN; N = HC;
                         tk = (tb & 7) * 32;  tn = (tb >> 3) * 32; }
    else if (tb < 384) { tb -= 128; W = W1; WT = w1T; K = HC; N = HC;
                         tk = (tb & 15) * 32; tn = (tb >> 4) * 32; }
    else               { tb -= 384; W = W2; WT = w2T; K = HC; N = NCLS;
                         tk = (tb & 15) * 32; tn = (tb >> 4) * 32; }
    int lx = threadIdx.x & 31, ly = threadIdx.x >> 5;   // 32 x 8
#pragma unroll
    for (int r = 0; r < 4; ++r) {
        int k = tk + ly + r * 8, n = tn + lx;
        tile[ly + r * 8][lx] = (k < K && n < N) ? (f16)W[(size_t)k * N + n] : (f16)0.f;
    }
    __syncthreads();
#pragma unroll
    for (int r = 0; r < 4; ++r) {
        int n = tn + ly + r * 8, k = tk + lx;
        if (n < N && k < K) WT[(size_t)n * K + k] = tile[lx][ly + r * 8];
    }
}

// ---------- GEMM + fused attn: B-resident LDS, barrier-free K-loop ----------
template <int K, bool AF32>
__global__ __launch_bounds__(512) void gemm_attn(const void* __restrict__ Aptr,
                                                 const f16* __restrict__ BT,
                                                 const float* __restrict__ a_src,
                                                 const float* __restrict__ a_dst,
                                                 f16* __restrict__ hx2,
                                                 float* __restrict__ al_s,
                                                 float* __restrict__ al_d) {
    constexpr int KK = K / 32;            // MFMA K-steps (16 or 8)
    constexpr int CH = K / 8;             // 16B chunks per B row (64 or 32)
    __shared__ f16 Bs[64 * K];            // 64 KB (K=512) / 32 KB (K=256)
    int t = threadIdx.x;
    int hp = blockIdx.x;                  // head pair
    int lane = t & 63, w = t >> 6;
    int fm = lane & 15, g = lane >> 4;
    int bm = blockIdx.y * 128 + w * 16;
    int row = bm + fm;
    bool rok = row < NN;

    f16x8 af[KK];
    if (AF32) {
        const float* A = (const float*)Aptr;
#pragma unroll
        for (int kk = 0; kk < KK; ++kk) {
            float4 lo = make_float4(0.f, 0.f, 0.f, 0.f), hi = lo;
            if (rok) {
                const float* ap = A + (size_t)row * K + kk * 32 + g * 8;
                lo = *(const float4*)ap;
                hi = *(const float4*)(ap + 4);
            }
            f16x8 v;
            v[0] = (f16)lo.x; v[1] = (f16)lo.y; v[2] = (f16)lo.z; v[3] = (f16)lo.w;
            v[4] = (f16)hi.x; v[5] = (f16)hi.y; v[6] = (f16)hi.z; v[7] = (f16)hi.w;
            af[kk] = v;
        }
    } else {
        const f16* A = (const f16*)Aptr;
#pragma unroll
        for (int kk = 0; kk < KK; ++kk) {
            uint4 r = rok ? *(const uint4*)(A + (size_t)row * K + kk * 32 + g * 8)
                          : make_uint4(0u, 0u, 0u, 0u);
            af[kk] = __builtin_bit_cast(f16x8, r);
        }
    }

    for (int sl = 0; sl < 2; ++sl) {
        int h = hp * 2 + sl;
        const f16* bsrc = BT + (size_t)h * 64 * K;
        for (int c = t; c < 64 * CH; c += 512) {
            int brow = c / CH;
            int j = c - brow * CH;
            uint4 v = *(const uint4*)(bsrc + (size_t)brow * K + j * 8);
            *(uint4*)&Bs[(size_t)brow * K + ((j ^ (brow & 7)) * 8)] = v;
        }
        __syncthreads();

        f32x4 acc[4] = {};
#pragma unroll
        for (int kk = 0; kk < KK; ++kk) {
#pragma unroll
            for (int nt = 0; nt < 4; ++nt) {
                f16x8 b = *(const f16x8*)
                    &Bs[(nt * 16 + fm) * K + (((kk * 4 + g) ^ (fm & 7)) * 8)];
                acc[nt] = MFMA16(af[kk], b, acc[nt]);
            }
        }

        float asc[4], adc[4];
#pragma unroll
        for (int nt = 0; nt < 4; ++nt) {
            asc[nt] = a_src[h * 64 + nt * 16 + fm];
            adc[nt] = a_dst[h * 64 + nt * 16 + fm];
        }
#pragma unroll
        for (int r = 0; r < 4; ++r) {
            int orow = bm + g * 4 + r;          // C/D: row=(lane>>4)*4+reg
            float s = acc[0][r] * asc[0] + acc[1][r] * asc[1] +
                      acc[2][r] * asc[2] + acc[3][r] * asc[3];
            float d = acc[0][r] * adc[0] + acc[1][r] * adc[1] +
                      acc[2][r] * adc[2] + acc[3][r] * adc[3];
#pragma unroll
            for (int off = 1; off < 16; off <<= 1) {
                s += __shfl_xor(s, off);
                d += __shfl_xor(d, off);
            }
            if (orow < NN) {
                if (fm == 0) {
                    al_s[orow * 8 + h] = s;
                    al_d[orow * 8 + h] = d;
                }
#pragma unroll
                for (int nt = 0; nt < 4; ++nt)
                    hx2[(size_t)orow * HC + h * 64 + nt * 16 + fm] =
                        (f16)acc[nt][r];
            }
        }
        __syncthreads();
    }
}

// ---------- layer 2: barrier-free B-resident GEMM 512->40 + fused attn ------
__global__ __launch_bounds__(256) void gemm2_attn(const f16* __restrict__ A,
                                                  const f16* __restrict__ BT,
                                                  const float* __restrict__ a_src2,
                                                  const float* __restrict__ a_dst2,
                                                  float* __restrict__ hx40,
                                                  float* __restrict__ als2,
                                                  float* __restrict__ ald2) {
    __shared__ f16 Bs[48 * HC];    // 48 KB, rows 40..47 zero
    int t = threadIdx.x;
    int lane = t & 63, w = t >> 6;
    int fm = lane & 15, g = lane >> 4;
    int bm = blockIdx.x * 64 + w * 16;
    int row = bm + fm;
    bool rok = row < NN;

    for (int c = t; c < 48 * 64; c += 256) {
        int brow = c >> 6, j = c & 63;
        uint4 v = make_uint4(0u, 0u, 0u, 0u);
        if (brow < NCLS) v = *(const uint4*)(BT + (size_t)brow * HC + j * 8);
        *(uint4*)&Bs[brow * HC + ((j ^ (brow & 7)) * 8)] = v;
    }

    f16x8 af[16];
#pragma unroll
    for (int kk = 0; kk < 16; ++kk) {
        uint4 r = rok ? *(const uint4*)(A + (size_t)row * HC + kk * 32 + g * 8)
                      : make_uint4(0u, 0u, 0u, 0u);
        af[kk] = __builtin_bit_cast(f16x8, r);
    }
    __syncthreads();

    f32x4 acc[3] = {};
#pragma unroll
    for (int kk = 0; kk < 16; ++kk) {
#pragma unroll
        for (int nt = 0; nt < 3; ++nt) {
            f16x8 b = *(const f16x8*)
                &Bs[(nt * 16 + fm) * HC + (((kk * 4 + g) ^ (fm & 7)) * 8)];
            acc[nt] = MFMA16(af[kk], b, acc[nt]);
        }
    }

    float a2s[3], a2d[3];
#pragma unroll
    for (int nt = 0; nt < 3; ++nt) {
        int col = nt * 16 + fm;
        a2s[nt] = (col < NCLS) ? a_src2[col] : 0.f;
        a2d[nt] = (col < NCLS) ? a_dst2[col] : 0.f;
    }
#pragma unroll
    for (int r = 0; r < 4; ++r) {
        int orow = bm + g * 4 + r;
        float s = acc[0][r] * a2s[0] + acc[1][r] * a2s[1] + acc[2][r] * a2s[2];
        float d = acc[0][r] * a2d[0] + acc[1][r] * a2d[1] + acc[2][r] * a2d[2];
#pragma unroll
        for (int off = 1; off < 16; off <<= 1) {
            s += __shfl_xor(s, off);
            d += __shfl_xor(d, off);
        }
        if (orow < NN) {
            if (fm == 0) { als2[orow] = s; ald2[orow] = d; }
#pragma unroll
            for (int nt = 0; nt < 3; ++nt) {
                int col = nt * 16 + fm;
                if (col < NCLS) hx40[(size_t)orow * NCLS + col] = acc[nt][r];
            }
        }
    }
}

// ---------- aggregate: 2 WAVES per node (even/odd ELL slots), LDS combine ----
__global__ __launch_bounds__(256) void agg_ell(const f16* __restrict__ hx2,
                                               const float* __restrict__ al_s,
                                               const float* __restrict__ al_d,
                                               const int* __restrict__ cnt,
                                               const int* __restrict__ ell,
                                               const float* __restrict__ bias,
                                               f16* __restrict__ outF) {
    __shared__ float accbuf[2][64][8];
    __shared__ float denbuf[2][64];
    int t = threadIdx.x;
    int lane = t & 63, w = t >> 6;
    int p = w >> 1, sub = w & 1;
    int n = blockIdx.x * 2 + p;
    bool nok = n < NN;
    int ch = lane * 8;          // 8 channels per lane; 64 lanes = 512 ch
    int h = lane >> 3;
    float acc[8] = {0.f, 0.f, 0.f, 0.f, 0.f, 0.f, 0.f, 0.f};
    float den = 0.f;
    if (nok) {
        float ald = al_d[n * HH + h];
        int dg = cnt[n]; if (dg > ELLW) dg = ELLW;
        const int* ep = ell + (size_t)n * ELLW;
        int i = sub;
        for (; i + 6 < dg; i += 8) {     // edges i, i+2, i+4, i+6
            int s0 = ep[i], s1 = ep[i + 2], s2 = ep[i + 4], s3 = ep[i + 6];
            float e0 = al_s[s0 * HH + h], e1 = al_s[s1 * HH + h];
            float e2 = al_s[s2 * HH + h], e3 = al_s[s3 * HH + h];
            uint4 v0 = *(const uint4*)(hx2 + (size_t)s0 * HC + ch);
            uint4 v1 = *(const uint4*)(hx2 + (size_t)s1 * HC + ch);
            uint4 v2 = *(const uint4*)(hx2 + (size_t)s2 * HC + ch);
            uint4 v3 = *(const uint4*)(hx2 + (size_t)s3 * HC + ch);
            e0 += ald; e0 = e0 > 0.f ? e0 : 0.2f * e0;
            e1 += ald; e1 = e1 > 0.f ? e1 : 0.2f * e1;
            e2 += ald; e2 = e2 > 0.f ? e2 : 0.2f * e2;
            e3 += ald; e3 = e3 > 0.f ? e3 : 0.2f * e3;
            float w0 = __expf(e0), w1 = __expf(e1);
            float w2 = __expf(e2), w3 = __expf(e3);
            f16x8 f0 = __builtin_bit_cast(f16x8, v0);
            f16x8 f1 = __builtin_bit_cast(f16x8, v1);
            f16x8 f2 = __builtin_bit_cast(f16x8, v2);
            f16x8 f3 = __builtin_bit_cast(f16x8, v3);
#pragma unroll
            for (int j = 0; j < 8; ++j)
                acc[j] += w0 * (float)f0[j] + w1 * (float)f1[j] +
                          w2 * (float)f2[j] + w3 * (float)f3[j];
            den += w0 + w1 + w2 + w3;
        }
        for (; i < dg; i += 2) {
            int s = ep[i];
            float e = al_s[s * HH + h] + ald;
            e = e > 0.f ? e : 0.2f * e;
            float wgt = __expf(e);
            uint4 v = *(const uint4*)(hx2 + (size_t)s * HC + ch);
            f16x8 f = __builtin_bit_cast(f16x8, v);
#pragma unroll
            for (int j = 0; j < 8; ++j) acc[j] += wgt * (float)f[j];
            den += wgt;
        }
    }
    if (sub == 1) {
#pragma unroll
        for (int j = 0; j < 8; ++j) accbuf[p][lane][j] = acc[j];
        denbuf[p][lane] = den;
    }
    __syncthreads();
    if (sub == 0 && nok) {
#pragma unroll
        for (int j = 0; j < 8; ++j) acc[j] += accbuf[p][lane][j];
        den += denbuf[p][lane];
        float inv = 1.f / (den + 1e-16f);
        float4 b0v = *(const float4*)(bias + ch);
        float4 b1v = *(const float4*)(bias + ch + 4);
        float bb[8] = {b0v.x, b0v.y, b0v.z, b0v.w, b1v.x, b1v.y, b1v.z, b1v.w};
        f16x8 o;
#pragma unroll
        for (int j = 0; j < 8; ++j) {
            float v = acc[j] * inv + bb[j];
            v = v > 0.f ? v : expm1f(v);        // ELU
            o[j] = (f16)v;
        }
        *(uint4*)(outF + (size_t)n * HC + ch) = __builtin_bit_cast(uint4, o);
    }
}

// ---------- final aggregate (H=1, C=40), 4 nodes/block ----------
__global__ __launch_bounds__(256) void agg2_final(const float* __restrict__ hx40,
                                                  const float* __restrict__ als,
                                                  const float* __restrict__ aldp,
                                                  const int* __restrict__ cnt,
                                                  const int* __restrict__ ell,
                                                  const float* __restrict__ b2,
                                                  float* __restrict__ out) {
    int w = threadIdx.x >> 6, c = threadIdx.x & 63;
    int n = blockIdx.x * 4 + w;
    if (n >= NN) return;
    float ald = aldp[n];
    int dg = cnt[n]; if (dg > ELLW) dg = ELLW;
    const int* ep = ell + (size_t)n * ELLW;
    float acc = 0.f, den = 0.f;
    int i = 0;
    for (; i + 4 <= dg; i += 4) {
        int s0 = ep[i], s1 = ep[i + 1], s2 = ep[i + 2], s3 = ep[i + 3];
        float e0 = als[s0], e1 = als[s1], e2 = als[s2], e3 = als[s3];
        float v0 = 0.f, v1 = 0.f, v2 = 0.f, v3 = 0.f;
        if (c < NCLS) {
            v0 = hx40[(size_t)s0 * NCLS + c];
            v1 = hx40[(size_t)s1 * NCLS + c];
            v2 = hx40[(size_t)s2 * NCLS + c];
            v3 = hx40[(size_t)s3 * NCLS + c];
        }
        e0 += ald; e0 = e0 > 0.f ? e0 : 0.2f * e0;
        e1 += ald; e1 = e1 > 0.f ? e1 : 0.2f * e1;
        e2 += ald; e2 = e2 > 0.f ? e2 : 0.2f * e2;
        e3 += ald; e3 = e3 > 0.f ? e3 : 0.2f * e3;
        float w0 = __expf(e0), w1 = __expf(e1), w2 = __expf(e2), w3 = __expf(e3);
        acc += w0 * v0 + w1 * v1 + w2 * v2 + w3 * v3;
        den += w0 + w1 + w2 + w3;
    }
    for (; i < dg; ++i) {
        int s = ep[i];
        float e = als[s] + ald;
        e = e > 0.f ? e : 0.2f * e;
        float wgt = __expf(e);
        if (c < NCLS) acc += wgt * hx40[(size_t)s * NCLS + c];
        den += wgt;
    }
    if (c < NCLS) out[(size_t)n * NCLS + c] = acc / (den + 1e-16f) + b2[c];
}

extern "C" void kernel_launch(void* const* d_in, const int* in_sizes, int n_in,
                              void* d_out, int out_size, void* d_ws, size_t ws_size,
                              hipStream_t stream) {
    const float* x   = (const float*)d_in[0];
    const int*   ei  = (const int*)  d_in[1];
    const float* W0  = (const float*)d_in[2];
    const float* as0 = (const float*)d_in[3];
    const float* ad0 = (const float*)d_in[4];
    const float* b0  = (const float*)d_in[5];
    const float* W1  = (const float*)d_in[6];
    const float* as1 = (const float*)d_in[7];
    const float* ad1 = (const float*)d_in[8];
    const float* b1  = (const float*)d_in[9];
    const float* W2  = (const float*)d_in[10];
    const float* as2 = (const float*)d_in[11];
    const float* ad2 = (const float*)d_in[12];
    const float* b2  = (const float*)d_in[13];
    float* out = (float*)d_out;

    char* p = (char*)d_ws;
    int* cnt  = (int*)p; p += 40064;
    int* ell  = (int*)p; p += (size_t)NN * ELLW * 4;    // 3.84 MB
    f16* w0T  = (f16*)p; p += HC * FIN * 2;
    f16* w1T  = (f16*)p; p += HC * HC * 2;
    f16* w2T  = (f16*)p; p += NCLS * HC * 2;
    f16* hxA  = (f16*)p; p += (size_t)NN * HC * 2;
    f16* hxB  = (f16*)p; p += (size_t)NN * HC * 2;
    f16* fA   = (f16*)p; p += (size_t)NN * HC * 2;
    f16* fB   = (f16*)p; p += (size_t)NN * HC * 2;
    float* hx40 = (float*)p; p += (size_t)NN * NCLS * 4;
    float* als0 = (float*)p; p += NN * HH * 4;
    float* ald0 = (float*)p; p += NN * HH * 4;
    float* als1 = (float*)p; p += NN * HH * 4;
    float* ald1 = (float*)p; p += NN * HH * 4;
    float* als2 = (float*)p; p += NN * 4;
    float* ald2 = (float*)p; p += NN * 4;

    const int NBR = (NN + 127) / 128;   // 79 row-chunks (layers 0/1)
    const int NAG = (NN + 1) / 2;       // 5000 blocks (2 waves/node agg)
    const int NB2 = (NN + 63) / 64;     // 157 row-blocks (layer 2)
    const int NPREP = SCAT_BLOCKS + 128 + 256 + 32;   // scatter + W0/W1/W2 tiles

    hipMemsetAsync(cnt, 0, NN * sizeof(int), stream);
    prep_kernel<<<NPREP, 256, 0, stream>>>(ei, cnt, ell, W0, W1, W2, w0T, w1T, w2T);

    dim3 gA(4, NBR);   // 4 head-pairs x 79 row-chunks = 316 blocks
    // layer 0
    gemm_attn<FIN, true><<<gA, 512, 0, stream>>>(x, w0T, as0, ad0, hxA, als0, ald0);
    agg_ell<<<NAG, 256, 0, stream>>>(hxA, als0, ald0, cnt, ell, b0, fA);
    // layer 1
    gemm_attn<HC, false><<<gA, 512, 0, stream>>>(fA, w1T, as1, ad1, hxB, als1, ald1);
    agg_ell<<<NAG, 256, 0, stream>>>(hxB, als1, ald1, cnt, ell, b1, fB);
    // layer 2
    gemm2_attn<<<NB2, 256, 0, stream>>>(fB, w2T, as2, ad2, hx40, als2, ald2);
    agg2_final<<<(NN + 3) / 4, 256, 0, stream>>>(hx40, als2, ald2, cnt, ell, b2, out);
}